// Round 20
// baseline (43.074 us; speedup 1.0000x reference)
//
#include <hip/hip_runtime.h>
#include <hip/hip_bf16.h>

// Chamfer distance via MFMA (bf16 hi/lo split, 3-term Ootomo precision).
// d(x,y) = |y|^2 - 2x.y + |x|^2 packed as a K=13 dot product in
// mfma_f32_32x32x16_bf16 (lanes<32 carry k=0..7 slots, lanes>=32 k=8..15).
// Math (prep tables, RED16, packing) verbatim rounds 4..19 (absmax 0.0).
//
// Round-20: DEDUP. dist1/dist2 are col-/row-mins of the SAME per-batch
// distance matrix; the old kernel computed it twice (swapped operands) so
// each direction's min was in-lane. New single pass (262144 MFMAs, half):
//   - wave owns 2 fixed y-tiles (A-frags const), streams x 2-tiles/iter
//   - x-mins: RED16 per MFMA into per-iter mdx (in-lane over rows) +
//     shfl_xor(32) + cross-wave LDS fold -> mintab[(b,ygrp)][x] (4 MB)
//   - y-mins: in-register fminf pairs across the whole x-loop, one
//     butterfly fold at the end -> ytab[xseg][point] (1 MB), plain stores
// ws = tabs 4 + mintab 4 + ytab 1 = 9.1 MB (< 12.6 MB proven available).
// Spill tell: chamfer_mfma FETCH >> 20 MB -> revert to r17 next round.
// r5/6 lesson: no inline asm touching MFMA results.

typedef float f32x16 __attribute__((ext_vector_type(16)));
typedef short bf16x8 __attribute__((ext_vector_type(8)));

constexpr int NPTS    = 8192;
constexpr int BATCH   = 4;
constexpr int NPT_TOT = 2 * BATCH * NPTS;   // 65536 table entries
constexpr int NRED    = 256;

__device__ __forceinline__ ushort bf16_rne(float v, float& back) {
    unsigned u = __float_as_uint(v);
    unsigned r = (u + 0x7FFFu + ((u >> 16) & 1u)) >> 16;
    back = __uint_as_float(r << 16);
    return (ushort)r;
}

union Frag { ushort u[8]; uint4 q; };

__global__ __launch_bounds__(256)
void chamfer_prep(const float* __restrict__ P1, const float* __restrict__ P2,
                  uint4* __restrict__ Atab, uint4* __restrict__ Btab) {
    const int p = blockIdx.x * 256 + threadIdx.x;          // 0..65535
    const int cloud = p >> 15;
    const float* src = (cloud ? P2 : P1) + (size_t)(p & (BATCH * NPTS - 1)) * 3;
    const float v0 = src[0], v1 = src[1], v2 = src[2];

    float h0f, h1f, h2f, d;
    const ushort h0 = bf16_rne(v0, h0f);
    const ushort h1 = bf16_rne(v1, h1f);
    const ushort h2 = bf16_rne(v2, h2f);
    const ushort l0 = bf16_rne(v0 - h0f, d);
    const ushort l1 = bf16_rne(v1 - h1f, d);
    const ushort l2 = bf16_rne(v2 - h2f, d);
    float n0f, n1f, n2f, m0f, m1f, m2f;
    const ushort n0 = bf16_rne(-2.f * h0f, n0f);
    const ushort n1 = bf16_rne(-2.f * h1f, n1f);
    const ushort n2 = bf16_rne(-2.f * h2f, n2f);
    float l0f, l1f, l2f;
    bf16_rne(v0 - h0f, l0f); bf16_rne(v1 - h1f, l1f); bf16_rne(v2 - h2f, l2f);
    const ushort m0 = bf16_rne(-2.f * l0f, m0f);
    const ushort m1 = bf16_rne(-2.f * l1f, m1f);
    const ushort m2 = bf16_rne(-2.f * l2f, m2f);
    const float s = fmaf(v0, v0, fmaf(v1, v1, v2 * v2));
    float shf;
    const ushort sh = bf16_rne(s, shf);
    const ushort sl = bf16_rne(s - shf, d);
    const ushort ONE = 0x3F80;

    Frag A0; A0.u[0]=h0; A0.u[1]=h1; A0.u[2]=h2; A0.u[3]=l0; A0.u[4]=l1; A0.u[5]=l2; A0.u[6]=h0; A0.u[7]=h1;
    Frag A1; A1.u[0]=h2; A1.u[1]=sh; A1.u[2]=sl; A1.u[3]=ONE; A1.u[4]=ONE; A1.u[5]=0; A1.u[6]=0; A1.u[7]=0;
    Frag B0; B0.u[0]=n0; B0.u[1]=n1; B0.u[2]=n2; B0.u[3]=n0; B0.u[4]=n1; B0.u[5]=n2; B0.u[6]=m0; B0.u[7]=m1;
    Frag B1; B1.u[0]=m2; B1.u[1]=ONE; B1.u[2]=ONE; B1.u[3]=sh; B1.u[4]=sl; B1.u[5]=0; B1.u[6]=0; B1.u[7]=0;

    Atab[p]           = A0.q;
    Atab[NPT_TOT + p] = A1.q;
    Btab[p]           = B0.q;
    Btab[NPT_TOT + p] = B1.q;
}

// 16 MFMA outputs + running min, min3-shaped fminf triples (clang -> v_min3_f32)
#define RED16(D, m) do {                                          \
    float a0 = fminf(fminf((D)[0],  (D)[1]),  (D)[2]);            \
    float a1 = fminf(fminf((D)[3],  (D)[4]),  (D)[5]);            \
    float a2 = fminf(fminf((D)[6],  (D)[7]),  (D)[8]);            \
    float a3 = fminf(fminf((D)[9],  (D)[10]), (D)[11]);           \
    float a4 = fminf(fminf((D)[12], (D)[13]), (D)[14]);           \
    float b0 = fminf(fminf(a0, a1), (D)[15]);                     \
    float b1 = fminf(fminf(a2, a3), a4);                          \
    (m) = fminf(fminf((m), b0), b1);                              \
} while (0)

__global__ __launch_bounds__(256, 4)
void chamfer_mfma(const uint4* __restrict__ Atab, const uint4* __restrict__ Btab,
                  float* __restrict__ mintab, float* __restrict__ ytab) {
    // 1024 blocks = 32 ygrp x 8 xseg x 4 b; XCD-swizzle: XCD k owns one
    // (b, xseg-half) -> A-slice 256 KB + B-slice 128 KB, L2-resident.
    const int l    = blockIdx.x;
    const int swz  = (l & 7) * 128 + (l >> 3);
    const int ygrp = swz & 31;
    const int xseg = (swz >> 5) & 7;
    const int b    = swz >> 8;

    const int tid = threadIdx.x, lane = tid & 63, w = tid >> 6;
    const int col = lane & 31, g = lane >> 5;   // g: k-half 0->slots 0-7, 1->8-15

    // rows: y = P2[b] (A operand); cols: x = P1[b] (B operand)
    const int ybase = (BATCH + b) * NPTS + ygrp * 256 + w * 64;
    const int xbase = b * NPTS + xseg * 1024;

    const bf16x8* At = (const bf16x8*)Atab;
    const bf16x8* Bt = (const bf16x8*)Btab;

    // fixed A-frags: this wave's two y-tiles (64 rows), loaded once
    const bf16x8 Af0 = At[(size_t)g * NPT_TOT + ybase + col];
    const bf16x8 Af1 = At[(size_t)g * NPT_TOT + ybase + 32 + col];

    float ym0[16], ym1[16];                     // per-row running mins (over x)
    #pragma unroll
    for (int i = 0; i < 16; ++i) ym0[i] = ym1[i] = 1e30f;

    __shared__ float lmd[4 * 64];
    const f32x16 zero = {};
    const size_t mrow = (size_t)(b * 32 + ygrp) * NPTS + (size_t)xseg * 1024;

    #pragma unroll 1
    for (int it = 0; it < 16; ++it) {
        const bf16x8 Bf0 = Bt[(size_t)g * NPT_TOT + xbase + it * 64 + col];
        const bf16x8 Bf1 = Bt[(size_t)g * NPT_TOT + xbase + it * 64 + 32 + col];
        float mdx0 = 1e30f, mdx1 = 1e30f;

        f32x16 Da = __builtin_amdgcn_mfma_f32_32x32x16_bf16(Af0, Bf0, zero, 0, 0, 0);
        f32x16 Db = __builtin_amdgcn_mfma_f32_32x32x16_bf16(Af0, Bf1, zero, 0, 0, 0);
        #pragma unroll
        for (int i = 0; i < 16; ++i) ym0[i] = fminf(fminf(ym0[i], Da[i]), Db[i]);
        RED16(Da, mdx0);
        RED16(Db, mdx1);
        Da = __builtin_amdgcn_mfma_f32_32x32x16_bf16(Af1, Bf0, zero, 0, 0, 0);
        Db = __builtin_amdgcn_mfma_f32_32x32x16_bf16(Af1, Bf1, zero, 0, 0, 0);
        #pragma unroll
        for (int i = 0; i < 16; ++i) ym1[i] = fminf(fminf(ym1[i], Da[i]), Db[i]);
        RED16(Da, mdx0);
        RED16(Db, mdx1);

        // x-mins: fold k-halves (full 64 rows of this wave), then cross-wave
        mdx0 = fminf(mdx0, __shfl_xor(mdx0, 32, 64));
        mdx1 = fminf(mdx1, __shfl_xor(mdx1, 32, 64));
        if (g == 0) { lmd[w * 64 + col] = mdx0; lmd[w * 64 + 32 + col] = mdx1; }
        __syncthreads();
        if (tid < 64) {
            float v = fminf(fminf(lmd[tid], lmd[64 + tid]),
                            fminf(lmd[128 + tid], lmd[192 + tid]));
            mintab[mrow + it * 64 + tid] = v;    // min over block's 256 y
        }
        __syncthreads();
    }

    // y-mins: butterfly fold across the 32 col-lanes (per k-half)
    #pragma unroll
    for (int off = 1; off < 32; off <<= 1) {
        #pragma unroll
        for (int i = 0; i < 16; ++i) {
            ym0[i] = fminf(ym0[i], __shfl_xor(ym0[i], off, 64));
            ym1[i] = fminf(ym1[i], __shfl_xor(ym1[i], off, 64));
        }
    }
    if (col == 0) {
        const int ytb = b * NPTS + ygrp * 256 + w * 64;   // batch-local point idx
        #pragma unroll
        for (int i = 0; i < 16; ++i) {
            const int r = (i & 3) + 8 * (i >> 2) + 4 * g;  // verified C/D row map
            ytab[(size_t)xseg * (BATCH * NPTS) + ytb + r]      = ym0[i];
            ytab[(size_t)xseg * (BATCH * NPTS) + ytb + 32 + r] = ym1[i];
        }
    }
}

__global__ __launch_bounds__(256)
void chamfer_reduce(const float* __restrict__ mintab, const float* __restrict__ ytab,
                    float* __restrict__ partials) {
    const int r = blockIdx.x * 256 + threadIdx.x;   // 0..65535
    float m = 1e30f;
    if (r < BATCH * NPTS) {                          // dist1: P1 points, 32 ygrp partials
        const int b = r >> 13, x = r & (NPTS - 1);
        #pragma unroll 4
        for (int yg = 0; yg < 32; ++yg)
            m = fminf(m, mintab[(size_t)(b * 32 + yg) * NPTS + x]);
    } else {                                         // dist2: P2 points, 8 xseg partials
        const int q = r - BATCH * NPTS;
        #pragma unroll
        for (int xs = 0; xs < 8; ++xs)
            m = fminf(m, ytab[(size_t)xs * (BATCH * NPTS) + q]);
    }
    float v = sqrtf(fmaxf(m, 0.f));
    #pragma unroll
    for (int off = 32; off; off >>= 1) v += __shfl_down(v, off, 64);
    __shared__ float ws[4];
    const int tid = threadIdx.x;
    if ((tid & 63) == 0) ws[tid >> 6] = v;
    __syncthreads();
    if (tid == 0)
        partials[blockIdx.x] = ws[0] + ws[1] + ws[2] + ws[3];   // plain store, no init
}

__global__ __launch_bounds__(256)
void chamfer_final(const float* __restrict__ partials, float* __restrict__ out) {
    const int tid = threadIdx.x;
    float v = partials[tid];                 // NRED == 256 == blockDim
    #pragma unroll
    for (int off = 32; off; off >>= 1) v += __shfl_down(v, off, 64);
    __shared__ float ws[4];
    if ((tid & 63) == 0) ws[tid >> 6] = v;
    __syncthreads();
    if (tid == 0)
        out[0] = (ws[0] + ws[1] + ws[2] + ws[3]) * (1.0f / NPT_TOT);
}

extern "C" void kernel_launch(void* const* d_in, const int* in_sizes, int n_in,
                              void* d_out, int out_size, void* d_ws, size_t ws_size,
                              hipStream_t stream) {
    const float* p1 = (const float*)d_in[0];
    const float* p2 = (const float*)d_in[1];
    float* out = (float*)d_out;

    const size_t tab_bytes = (size_t)2 * NPT_TOT * 16;           // 2 MB each
    uint4* Atab   = (uint4*)d_ws;
    uint4* Btab   = (uint4*)((char*)d_ws + tab_bytes);
    float* mintab = (float*)((char*)d_ws + 2 * tab_bytes);       // 4 MB (128 x 8192)
    float* ytab   = (float*)((char*)mintab + (size_t)128 * NPTS * 4);   // 1 MB
    float* partials = (float*)((char*)ytab + (size_t)8 * BATCH * NPTS * 4);

    chamfer_prep<<<dim3(NPT_TOT / 256), 256, 0, stream>>>(p1, p2, Atab, Btab);
    chamfer_mfma<<<dim3(1024), 256, 0, stream>>>(Atab, Btab, mintab, ytab);
    chamfer_reduce<<<dim3(NRED), 256, 0, stream>>>(mintab, ytab, partials);
    chamfer_final<<<1, 256, 0, stream>>>(partials, out);
}

// Round 21
// 41.284 us; speedup vs baseline: 1.0434x; 1.0434x over previous
//
#include <hip/hip_runtime.h>
#include <hip/hip_bf16.h>

// Chamfer distance via MFMA (bf16 hi/lo split, 3-term Ootomo precision).
// d(x,y) = |y|^2 - 2x.y + |x|^2 packed as a K=13 dot product in
// mfma_f32_32x32x16_bf16 (lanes<32 carry k=0..7 slots, lanes>=32 k=8..15).
// Math (prep tables, RED16, packing, C/D row map) verbatim r4..r20 (absmax 0).
//
// Round-21 = r20 dedup (single pass serves both chamfer directions; 262144
// MFMAs, half of r17) with the two r20 throttles removed:
//   (1) barrier-free loop: per-wave x-min partials go to private LDS slots
//       lmd[it][w*64+x]; ONE __syncthreads() + one fold pass after the loop
//       (was 2 barriers x 16 iters = 32).
//   (2) __launch_bounds__(256,2): ~132 regs demanded (ym 32 + D 32 + Af/Bf 32
//       + temps) fits the 256 budget; r20's (256,4)=128 cap spilled.
// No LDS A-staging (A-frags are 2 fixed regs/wave); LDS = 16KB lmd only.
// Fallback documented: if flat/regressed -> revert to r17 (29.1us) and stop.
// r5/6 lesson: no inline asm touching MFMA results.

typedef float f32x16 __attribute__((ext_vector_type(16)));
typedef short bf16x8 __attribute__((ext_vector_type(8)));

constexpr int NPTS    = 8192;
constexpr int BATCH   = 4;
constexpr int NPT_TOT = 2 * BATCH * NPTS;   // 65536 table entries
constexpr int NRED    = 256;

__device__ __forceinline__ ushort bf16_rne(float v, float& back) {
    unsigned u = __float_as_uint(v);
    unsigned r = (u + 0x7FFFu + ((u >> 16) & 1u)) >> 16;
    back = __uint_as_float(r << 16);
    return (ushort)r;
}

union Frag { ushort u[8]; uint4 q; };

__global__ __launch_bounds__(256)
void chamfer_prep(const float* __restrict__ P1, const float* __restrict__ P2,
                  uint4* __restrict__ Atab, uint4* __restrict__ Btab) {
    const int p = blockIdx.x * 256 + threadIdx.x;          // 0..65535
    const int cloud = p >> 15;
    const float* src = (cloud ? P2 : P1) + (size_t)(p & (BATCH * NPTS - 1)) * 3;
    const float v0 = src[0], v1 = src[1], v2 = src[2];

    float h0f, h1f, h2f, d;
    const ushort h0 = bf16_rne(v0, h0f);
    const ushort h1 = bf16_rne(v1, h1f);
    const ushort h2 = bf16_rne(v2, h2f);
    const ushort l0 = bf16_rne(v0 - h0f, d);
    const ushort l1 = bf16_rne(v1 - h1f, d);
    const ushort l2 = bf16_rne(v2 - h2f, d);
    float n0f, n1f, n2f, m0f, m1f, m2f;
    const ushort n0 = bf16_rne(-2.f * h0f, n0f);
    const ushort n1 = bf16_rne(-2.f * h1f, n1f);
    const ushort n2 = bf16_rne(-2.f * h2f, n2f);
    float l0f, l1f, l2f;
    bf16_rne(v0 - h0f, l0f); bf16_rne(v1 - h1f, l1f); bf16_rne(v2 - h2f, l2f);
    const ushort m0 = bf16_rne(-2.f * l0f, m0f);
    const ushort m1 = bf16_rne(-2.f * l1f, m1f);
    const ushort m2 = bf16_rne(-2.f * l2f, m2f);
    const float s = fmaf(v0, v0, fmaf(v1, v1, v2 * v2));
    float shf;
    const ushort sh = bf16_rne(s, shf);
    const ushort sl = bf16_rne(s - shf, d);
    const ushort ONE = 0x3F80;

    Frag A0; A0.u[0]=h0; A0.u[1]=h1; A0.u[2]=h2; A0.u[3]=l0; A0.u[4]=l1; A0.u[5]=l2; A0.u[6]=h0; A0.u[7]=h1;
    Frag A1; A1.u[0]=h2; A1.u[1]=sh; A1.u[2]=sl; A1.u[3]=ONE; A1.u[4]=ONE; A1.u[5]=0; A1.u[6]=0; A1.u[7]=0;
    Frag B0; B0.u[0]=n0; B0.u[1]=n1; B0.u[2]=n2; B0.u[3]=n0; B0.u[4]=n1; B0.u[5]=n2; B0.u[6]=m0; B0.u[7]=m1;
    Frag B1; B1.u[0]=m2; B1.u[1]=ONE; B1.u[2]=ONE; B1.u[3]=sh; B1.u[4]=sl; B1.u[5]=0; B1.u[6]=0; B1.u[7]=0;

    Atab[p]           = A0.q;
    Atab[NPT_TOT + p] = A1.q;
    Btab[p]           = B0.q;
    Btab[NPT_TOT + p] = B1.q;
}

// 16 MFMA outputs + running min, min3-shaped fminf triples (clang -> v_min3_f32)
#define RED16(D, m) do {                                          \
    float a0 = fminf(fminf((D)[0],  (D)[1]),  (D)[2]);            \
    float a1 = fminf(fminf((D)[3],  (D)[4]),  (D)[5]);            \
    float a2 = fminf(fminf((D)[6],  (D)[7]),  (D)[8]);            \
    float a3 = fminf(fminf((D)[9],  (D)[10]), (D)[11]);           \
    float a4 = fminf(fminf((D)[12], (D)[13]), (D)[14]);           \
    float b0 = fminf(fminf(a0, a1), (D)[15]);                     \
    float b1 = fminf(fminf(a2, a3), a4);                          \
    (m) = fminf(fminf((m), b0), b1);                              \
} while (0)

__global__ __launch_bounds__(256, 2)
void chamfer_mfma(const uint4* __restrict__ Atab, const uint4* __restrict__ Btab,
                  float* __restrict__ mintab, float* __restrict__ ytab) {
    // 1024 blocks = 32 ygrp x 8 xseg x 4 b; XCD-swizzle: XCD k owns one
    // (b, xseg-half) -> A-slice 256 KB + B-slice 128 KB, L2-resident.
    const int l    = blockIdx.x;
    const int swz  = (l & 7) * 128 + (l >> 3);
    const int ygrp = swz & 31;
    const int xseg = (swz >> 5) & 7;
    const int b    = swz >> 8;

    const int tid = threadIdx.x, lane = tid & 63, w = tid >> 6;
    const int col = lane & 31, g = lane >> 5;   // g: k-half 0->slots 0-7, 1->8-15

    // rows: y = P2[b] (A operand); cols: x = P1[b] (B operand)
    const int ybase = (BATCH + b) * NPTS + ygrp * 256 + w * 64;
    const int xbase = b * NPTS + xseg * 1024;

    const bf16x8* At = (const bf16x8*)Atab;
    const bf16x8* Bt = (const bf16x8*)Btab;

    // fixed A-frags: this wave's two y-tiles (64 rows), loaded once
    const bf16x8 Af0 = At[(size_t)g * NPT_TOT + ybase + col];
    const bf16x8 Af1 = At[(size_t)g * NPT_TOT + ybase + 32 + col];

    float ym0[16], ym1[16];                     // per-row running mins (over x)
    #pragma unroll
    for (int i = 0; i < 16; ++i) ym0[i] = ym1[i] = 1e30f;

    __shared__ float lmd[16 * 256];             // 16 KB: [it][w*64 + x]
    const f32x16 zero = {};

    #pragma unroll 1
    for (int it = 0; it < 16; ++it) {
        const bf16x8 Bf0 = Bt[(size_t)g * NPT_TOT + xbase + it * 64 + col];
        const bf16x8 Bf1 = Bt[(size_t)g * NPT_TOT + xbase + it * 64 + 32 + col];
        float mdx0 = 1e30f, mdx1 = 1e30f;

        f32x16 Da = __builtin_amdgcn_mfma_f32_32x32x16_bf16(Af0, Bf0, zero, 0, 0, 0);
        f32x16 Db = __builtin_amdgcn_mfma_f32_32x32x16_bf16(Af0, Bf1, zero, 0, 0, 0);
        #pragma unroll
        for (int i = 0; i < 16; ++i) ym0[i] = fminf(fminf(ym0[i], Da[i]), Db[i]);
        RED16(Da, mdx0);
        RED16(Db, mdx1);
        Da = __builtin_amdgcn_mfma_f32_32x32x16_bf16(Af1, Bf0, zero, 0, 0, 0);
        Db = __builtin_amdgcn_mfma_f32_32x32x16_bf16(Af1, Bf1, zero, 0, 0, 0);
        #pragma unroll
        for (int i = 0; i < 16; ++i) ym1[i] = fminf(fminf(ym1[i], Da[i]), Db[i]);
        RED16(Da, mdx0);
        RED16(Db, mdx1);

        // fold k-halves (this wave's full 64 rows); stash per-wave partial.
        // each wave writes only its own lmd slots -> NO barrier in the loop.
        mdx0 = fminf(mdx0, __shfl_xor(mdx0, 32, 64));
        mdx1 = fminf(mdx1, __shfl_xor(mdx1, 32, 64));
        if (g == 0) {
            lmd[it * 256 + w * 64 + col]      = mdx0;
            lmd[it * 256 + w * 64 + 32 + col] = mdx1;
        }
    }

    __syncthreads();                            // the ONLY barrier

    // cross-wave fold: 16 iters x 64 x = 1024 items / 256 threads = 4 each
    const size_t mrow = (size_t)(b * 32 + ygrp) * NPTS + (size_t)xseg * 1024;
    #pragma unroll
    for (int k = 0; k < 4; ++k) {
        const int item = k * 256 + tid;         // 0..1023
        const int it = item >> 6, x = item & 63;
        const float* p = lmd + it * 256;
        float v = fminf(fminf(p[x], p[64 + x]), fminf(p[128 + x], p[192 + x]));
        mintab[mrow + it * 64 + x] = v;         // min over block's 256 y
    }

    // y-mins: butterfly fold across the 32 col-lanes (per k-half)
    #pragma unroll
    for (int off = 1; off < 32; off <<= 1) {
        #pragma unroll
        for (int i = 0; i < 16; ++i) {
            ym0[i] = fminf(ym0[i], __shfl_xor(ym0[i], off, 64));
            ym1[i] = fminf(ym1[i], __shfl_xor(ym1[i], off, 64));
        }
    }
    if (col == 0) {
        const int ytb = b * NPTS + ygrp * 256 + w * 64;   // batch-local point idx
        #pragma unroll
        for (int i = 0; i < 16; ++i) {
            const int r = (i & 3) + 8 * (i >> 2) + 4 * g;  // verified C/D row map
            ytab[(size_t)xseg * (BATCH * NPTS) + ytb + r]      = ym0[i];
            ytab[(size_t)xseg * (BATCH * NPTS) + ytb + 32 + r] = ym1[i];
        }
    }
}

__global__ __launch_bounds__(256)
void chamfer_reduce(const float* __restrict__ mintab, const float* __restrict__ ytab,
                    float* __restrict__ partials) {
    const int r = blockIdx.x * 256 + threadIdx.x;   // 0..65535
    float m = 1e30f;
    if (r < BATCH * NPTS) {                          // dist1: P1 points, 32 ygrp partials
        const int b = r >> 13, x = r & (NPTS - 1);
        #pragma unroll 4
        for (int yg = 0; yg < 32; ++yg)
            m = fminf(m, mintab[(size_t)(b * 32 + yg) * NPTS + x]);
    } else {                                         // dist2: P2 points, 8 xseg partials
        const int q = r - BATCH * NPTS;
        #pragma unroll
        for (int xs = 0; xs < 8; ++xs)
            m = fminf(m, ytab[(size_t)xs * (BATCH * NPTS) + q]);
    }
    float v = sqrtf(fmaxf(m, 0.f));
    #pragma unroll
    for (int off = 32; off; off >>= 1) v += __shfl_down(v, off, 64);
    __shared__ float ws[4];
    const int tid = threadIdx.x;
    if ((tid & 63) == 0) ws[tid >> 6] = v;
    __syncthreads();
    if (tid == 0)
        partials[blockIdx.x] = ws[0] + ws[1] + ws[2] + ws[3];   // plain store, no init
}

__global__ __launch_bounds__(256)
void chamfer_final(const float* __restrict__ partials, float* __restrict__ out) {
    const int tid = threadIdx.x;
    float v = partials[tid];                 // NRED == 256 == blockDim
    #pragma unroll
    for (int off = 32; off; off >>= 1) v += __shfl_down(v, off, 64);
    __shared__ float ws[4];
    if ((tid & 63) == 0) ws[tid >> 6] = v;
    __syncthreads();
    if (tid == 0)
        out[0] = (ws[0] + ws[1] + ws[2] + ws[3]) * (1.0f / NPT_TOT);
}

extern "C" void kernel_launch(void* const* d_in, const int* in_sizes, int n_in,
                              void* d_out, int out_size, void* d_ws, size_t ws_size,
                              hipStream_t stream) {
    const float* p1 = (const float*)d_in[0];
    const float* p2 = (const float*)d_in[1];
    float* out = (float*)d_out;

    const size_t tab_bytes = (size_t)2 * NPT_TOT * 16;           // 2 MB each
    uint4* Atab   = (uint4*)d_ws;
    uint4* Btab   = (uint4*)((char*)d_ws + tab_bytes);
    float* mintab = (float*)((char*)d_ws + 2 * tab_bytes);       // 4 MB (128 x 8192)
    float* ytab   = (float*)((char*)mintab + (size_t)128 * NPTS * 4);   // 1 MB
    float* partials = (float*)((char*)ytab + (size_t)8 * BATCH * NPTS * 4);

    chamfer_prep<<<dim3(NPT_TOT / 256), 256, 0, stream>>>(p1, p2, Atab, Btab);
    chamfer_mfma<<<dim3(1024), 256, 0, stream>>>(Atab, Btab, mintab, ytab);
    chamfer_reduce<<<dim3(NRED), 256, 0, stream>>>(mintab, ytab, partials);
    chamfer_final<<<1, 256, 0, stream>>>(partials, out);
}

// Round 22
// 29.287 us; speedup vs baseline: 1.4708x; 1.4097x over previous
//
#include <hip/hip_runtime.h>
#include <hip/hip_bf16.h>

// Chamfer distance via MFMA (bf16 hi/lo split, 3-term Ootomo precision).
// d(x,y) = |y|^2 - 2x.y + |x|^2 packed as a K=13 dot product in
// mfma_f32_32x32x16_bf16 (lanes<32 carry k=0..7 slots, lanes>=32 k=8..15).
// Min over y: in-lane min3 tree over the 16 accumulator regs + shfl_xor(32).
// Math verbatim rounds 4..21 (absmax 0.0 every passing round).
//
// FINAL (= round-17, session best 29.1us; reverted after r18-r21 probes):
// The kernel is VALU-dependency-bound: per MFMA the compiler emits 16
// v_accvgpr_read (AGPR->VGPR shuttle) + 8 v_min3_f32. Structural floor at
// this codegen: VALU 10.2us@100% + MFMA pipe 6.9us (overlapped), observed
// ~60% VALU efficiency -> ~23us kernel. Levers tested and null/worse:
// launch-bounds 64/128/256-reg (r7/r15/r19), ds_read prefetch (r13/r15),
// D ping-pong depth (r14/r17), reduce shape (r18), dedup (r20/r21),
// occupancy 4<->8 waves/SIMD. Past this requires inline-asm MFMA with VGPR
// accumulators (excluded: r5/6 hazard) or disasm-driven ISA work.

typedef float f32x16 __attribute__((ext_vector_type(16)));
typedef short bf16x8 __attribute__((ext_vector_type(8)));

constexpr int NPTS    = 8192;
constexpr int BATCH   = 4;
constexpr int NPT_TOT = 2 * BATCH * NPTS;   // 65536 rows total
constexpr int NRED    = 256;
constexpr int YSEG    = 8;                  // 1024 y-pts per block segment
constexpr int SEG     = NPTS / YSEG;        // 1024
constexpr int YI      = SEG / 32;           // 32

__device__ __forceinline__ ushort bf16_rne(float v, float& back) {
    unsigned u = __float_as_uint(v);
    unsigned r = (u + 0x7FFFu + ((u >> 16) & 1u)) >> 16;
    back = __uint_as_float(r << 16);
    return (ushort)r;
}

union Frag { ushort u[8]; uint4 q; };

__global__ __launch_bounds__(256)
void chamfer_prep(const float* __restrict__ P1, const float* __restrict__ P2,
                  uint4* __restrict__ Atab, uint4* __restrict__ Btab) {
    const int p = blockIdx.x * 256 + threadIdx.x;          // 0..65535
    const int cloud = p >> 15;
    const float* src = (cloud ? P2 : P1) + (size_t)(p & (BATCH * NPTS - 1)) * 3;
    const float v0 = src[0], v1 = src[1], v2 = src[2];

    float h0f, h1f, h2f, d;
    const ushort h0 = bf16_rne(v0, h0f);
    const ushort h1 = bf16_rne(v1, h1f);
    const ushort h2 = bf16_rne(v2, h2f);
    const ushort l0 = bf16_rne(v0 - h0f, d);
    const ushort l1 = bf16_rne(v1 - h1f, d);
    const ushort l2 = bf16_rne(v2 - h2f, d);
    float n0f, n1f, n2f, m0f, m1f, m2f;
    const ushort n0 = bf16_rne(-2.f * h0f, n0f);
    const ushort n1 = bf16_rne(-2.f * h1f, n1f);
    const ushort n2 = bf16_rne(-2.f * h2f, n2f);
    float l0f, l1f, l2f;
    bf16_rne(v0 - h0f, l0f); bf16_rne(v1 - h1f, l1f); bf16_rne(v2 - h2f, l2f);
    const ushort m0 = bf16_rne(-2.f * l0f, m0f);
    const ushort m1 = bf16_rne(-2.f * l1f, m1f);
    const ushort m2 = bf16_rne(-2.f * l2f, m2f);
    const float s = fmaf(v0, v0, fmaf(v1, v1, v2 * v2));
    float shf;
    const ushort sh = bf16_rne(s, shf);
    const ushort sl = bf16_rne(s - shf, d);
    const ushort ONE = 0x3F80;

    Frag A0; A0.u[0]=h0; A0.u[1]=h1; A0.u[2]=h2; A0.u[3]=l0; A0.u[4]=l1; A0.u[5]=l2; A0.u[6]=h0; A0.u[7]=h1;
    Frag A1; A1.u[0]=h2; A1.u[1]=sh; A1.u[2]=sl; A1.u[3]=ONE; A1.u[4]=ONE; A1.u[5]=0; A1.u[6]=0; A1.u[7]=0;
    Frag B0; B0.u[0]=n0; B0.u[1]=n1; B0.u[2]=n2; B0.u[3]=n0; B0.u[4]=n1; B0.u[5]=n2; B0.u[6]=m0; B0.u[7]=m1;
    Frag B1; B1.u[0]=m2; B1.u[1]=ONE; B1.u[2]=ONE; B1.u[3]=sh; B1.u[4]=sl; B1.u[5]=0; B1.u[6]=0; B1.u[7]=0;

    Atab[p]           = A0.q;
    Atab[NPT_TOT + p] = A1.q;
    Btab[p]           = B0.q;
    Btab[NPT_TOT + p] = B1.q;
}

// 16 MFMA outputs + running min, min3-shaped fminf triples (clang -> v_min3_f32)
#define RED16(D, m) do {                                          \
    float a0 = fminf(fminf((D)[0],  (D)[1]),  (D)[2]);            \
    float a1 = fminf(fminf((D)[3],  (D)[4]),  (D)[5]);            \
    float a2 = fminf(fminf((D)[6],  (D)[7]),  (D)[8]);            \
    float a3 = fminf(fminf((D)[9],  (D)[10]), (D)[11]);           \
    float a4 = fminf(fminf((D)[12], (D)[13]), (D)[14]);           \
    float b0 = fminf(fminf(a0, a1), (D)[15]);                     \
    float b1 = fminf(fminf(a2, a3), a4);                          \
    (m) = fminf(fminf((m), b0), b1);                              \
} while (0)

__global__ __launch_bounds__(256, 4)
void chamfer_mfma(const uint4* __restrict__ Atab, const uint4* __restrict__ Btab,
                  float* __restrict__ mintab) {
    constexpr int NWG = 16 * 8 * YSEG;        // 1024 blocks: ONE generation
    constexpr int CPX = NWG / 8;              // 128 blocks per XCD chunk

    // XCD-aware bijective swizzle: XCD k gets swz in [k*CPX,(k+1)*CPX) == comb k.
    const int l   = blockIdx.x;
    const int swz = (l & 7) * CPX + (l >> 3);
    const int xblk = swz & 15;                // 0..15  (512 x-points per block)
    const int yseg = (swz >> 4) & (YSEG - 1); // 0..7
    const int comb = swz >> 7;                // 0..7  dir*4+b

    const int tid  = threadIdx.x;
    const int lane = tid & 63;
    const int w    = tid >> 6;
    const int col  = lane & 31;
    const int g    = lane >> 5;          // k-half: 0 -> slots 0-7, 1 -> slots 8-15

    const int dir  = comb >> 2;
    const int b    = comb & 3;

    const int xbase = (dir * BATCH + b) * NPTS + xblk * 512 + w * 128;
    const int ybase = ((1 - dir) * BATCH + b) * NPTS + yseg * SEG;

    // ---- stage this block's A-segment (both k-halves) into LDS, once ----
    __shared__ uint4 lds_a[2 * SEG];          // 32 KB
    const uint4* As0 = Atab + ybase;
    const uint4* As1 = Atab + NPT_TOT + ybase;
    #pragma unroll
    for (int i = 0; i < SEG / 256; ++i) {
        lds_a[i * 256 + tid]       = As0[i * 256 + tid];
        lds_a[SEG + i * 256 + tid] = As1[i * 256 + tid];
    }

    // 4 B-fragments (128 x-points) in registers — loaded once, L2-resident
    const bf16x8* Bt = (const bf16x8*)Btab;
    bf16x8 Bf[4];
    #pragma unroll
    for (int t = 0; t < 4; ++t)
        Bf[t] = Bt[(size_t)g * NPT_TOT + xbase + t * 32 + col];

    float md[4];
    #pragma unroll
    for (int t = 0; t < 4; ++t) md[t] = 1e30f;

    __syncthreads();

    // ---- main loop: prefetch + Da/Db ping-pong (RED16(t) overlaps MFMA(t+1)) ----
    const f32x16 zero = {};
    const int lbase = g * SEG + col;
    uint4 Afq = lds_a[lbase];                 // prefetch yi=0
    #pragma unroll 2
    for (int yi = 0; yi < YI; ++yi) {
        const uint4 Afc = Afq;
        if (yi + 1 < YI) Afq = lds_a[lbase + (yi + 1) * 32];
        bf16x8 Af;
        __builtin_memcpy(&Af, &Afc, 16);
        f32x16 Da = __builtin_amdgcn_mfma_f32_32x32x16_bf16(Af, Bf[0], zero, 0, 0, 0);
        f32x16 Db = __builtin_amdgcn_mfma_f32_32x32x16_bf16(Af, Bf[1], zero, 0, 0, 0);
        RED16(Da, md[0]);
        Da = __builtin_amdgcn_mfma_f32_32x32x16_bf16(Af, Bf[2], zero, 0, 0, 0);
        RED16(Db, md[1]);
        Db = __builtin_amdgcn_mfma_f32_32x32x16_bf16(Af, Bf[3], zero, 0, 0, 0);
        RED16(Da, md[2]);
        RED16(Db, md[3]);
    }

    // fold half-waves: both k-halves then hold the min over all 32 y-rows
    #pragma unroll
    for (int t = 0; t < 4; ++t)
        md[t] = fminf(md[t], __shfl_xor(md[t], 32, 64));

    if (g == 0) {
        const size_t rowbase = (size_t)yseg * NPT_TOT + xbase;
        #pragma unroll
        for (int t = 0; t < 4; ++t)
            mintab[rowbase + t * 32 + col] = md[t];
    }
}

__global__ __launch_bounds__(256)
void chamfer_reduce(const float* __restrict__ mintab, float* __restrict__ partials) {
    const int r = blockIdx.x * 256 + threadIdx.x;
    float m = mintab[r];
    #pragma unroll
    for (int s = 1; s < YSEG; ++s)
        m = fminf(m, mintab[(size_t)s * NPT_TOT + r]);
    float v = sqrtf(fmaxf(m, 0.f));
    #pragma unroll
    for (int off = 32; off; off >>= 1) v += __shfl_down(v, off, 64);
    __shared__ float ws[4];
    const int tid = threadIdx.x;
    if ((tid & 63) == 0) ws[tid >> 6] = v;
    __syncthreads();
    if (tid == 0)
        partials[blockIdx.x] = ws[0] + ws[1] + ws[2] + ws[3];   // plain store, no init
}

__global__ __launch_bounds__(256)
void chamfer_final(const float* __restrict__ partials, float* __restrict__ out) {
    const int tid = threadIdx.x;
    float v = partials[tid];                 // NRED == 256 == blockDim
    #pragma unroll
    for (int off = 32; off; off >>= 1) v += __shfl_down(v, off, 64);
    __shared__ float ws[4];
    if ((tid & 63) == 0) ws[tid >> 6] = v;
    __syncthreads();
    if (tid == 0)
        out[0] = (ws[0] + ws[1] + ws[2] + ws[3]) * (1.0f / NPT_TOT);
}

extern "C" void kernel_launch(void* const* d_in, const int* in_sizes, int n_in,
                              void* d_out, int out_size, void* d_ws, size_t ws_size,
                              hipStream_t stream) {
    const float* p1 = (const float*)d_in[0];
    const float* p2 = (const float*)d_in[1];
    float* out = (float*)d_out;

    const size_t tab_bytes = (size_t)2 * NPT_TOT * 16;          // 2 MB each
    uint4* Atab   = (uint4*)d_ws;
    uint4* Btab   = (uint4*)((char*)d_ws + tab_bytes);
    float* mintab = (float*)((char*)d_ws + 2 * tab_bytes);      // 2 MB @ YSEG=8
    float* partials = (float*)((char*)mintab + (size_t)YSEG * NPT_TOT * 4);

    chamfer_prep<<<dim3(NPT_TOT / 256), 256, 0, stream>>>(p1, p2, Atab, Btab);
    chamfer_mfma<<<dim3(16 * 8 * YSEG), 256, 0, stream>>>(Atab, Btab, mintab);
    chamfer_reduce<<<dim3(NRED), 256, 0, stream>>>(mintab, partials);
    chamfer_final<<<1, 256, 0, stream>>>(partials, out);
}